// Round 5
// baseline (1619.918 us; speedup 1.0000x reference)
//
// EpisodicMemory: fp32 inputs/output.
//   prep_w    : one-shot fp32->bf16 of fc1_w, W_ih, W_hh.
//   g_kernel  : per-b block, feat@fc1w^T -> tanh -> fc2 -> sigmoid -> G (unchanged from R4).
//   xg_kernel : chunked GEMM xg[b,sl,1536] = C[:,t,:]@Wih^T (bf16 out), 128x256 tiles,
//               double-buffered LDS pipeline. 8 chunks of 8 timesteps (25 MB buffer reused).
//   scan_step : per t. gates = xg + h@Whh^T (h bf16 hi+lo, double-buffered state).
//               Staging/step/block: 141 KB (was 448): h 128K + Whh 96K + xg 12K. 6 MFMAs/pair.
//               Double-buffered LDS chunk pipeline (prefetch regs during MFMA).
#include <hip/hip_runtime.h>
#include <hip/hip_bf16.h>

#define H_ 512
#define SH_ 120
#define B_ 1024
#define S_ 64

typedef __bf16 bf16x8 __attribute__((ext_vector_type(8)));
typedef float floatx4 __attribute__((ext_vector_type(4)));

__device__ __forceinline__ float bf2f(ushort u) {
    union { unsigned int i; float f; } v; v.i = ((unsigned int)u) << 16; return v.f;
}
__device__ __forceinline__ ushort f2bf(float f) {
    union { float f; unsigned int i; } v; v.f = f;
    unsigned int x = v.i;
    unsigned int r = (x + 0x7fffu + ((x >> 16) & 1u)) >> 16;  // RNE
    return (ushort)r;
}
__device__ __forceinline__ ushort f2bf_fast(float f) {       // native cvt (RNE on gfx950)
    __bf16 b = (__bf16)f;
    union { __bf16 b; ushort u; } v; v.b = b; return v.u;
}

// ---------------------------------------------------------------------------
// prep_w: one-shot fp32 -> bf16 of the three weight matrices.
// ---------------------------------------------------------------------------
__global__ __launch_bounds__(256) void prep_w(
    const float* __restrict__ fc1w, ushort* __restrict__ fc1wb,
    const float* __restrict__ Wih,  ushort* __restrict__ Wihb,
    const float* __restrict__ Whh,  ushort* __restrict__ Whhb)
{
    const int stride = gridDim.x * blockDim.x;
    const int tid = blockIdx.x * blockDim.x + threadIdx.x;
    for (int i = tid; i < 61440; i += stride) {            // 120*2048/4
        const float4 v = ((const float4*)fc1w)[i];
        ushort4 o; o.x = f2bf(v.x); o.y = f2bf(v.y); o.z = f2bf(v.z); o.w = f2bf(v.w);
        ((ushort4*)fc1wb)[i] = o;
    }
    for (int i = tid; i < 196608; i += stride) {           // 1536*512/4
        const float4 v = ((const float4*)Wih)[i];
        ushort4 o; o.x = f2bf(v.x); o.y = f2bf(v.y); o.z = f2bf(v.z); o.w = f2bf(v.w);
        ((ushort4*)Wihb)[i] = o;
    }
    for (int i = tid; i < 196608; i += stride) {
        const float4 v = ((const float4*)Whh)[i];
        ushort4 o; o.x = f2bf(v.x); o.y = f2bf(v.y); o.z = f2bf(v.z); o.w = f2bf(v.w);
        ((ushort4*)Whhb)[i] = o;
    }
}

// ---------------------------------------------------------------------------
// G kernel: one block per b (unchanged from R4, passing at 127 us).
// ---------------------------------------------------------------------------
__global__ __launch_bounds__(256) void g_kernel(
    const float* __restrict__ C, const float* __restrict__ Q,
    const float* __restrict__ M, const ushort* __restrict__ fc1wb,
    const float* __restrict__ fc1b, const float* __restrict__ fc2w,
    const float* __restrict__ fc2b, float* __restrict__ G)
{
    __shared__ float qrow[H_];
    __shared__ float mrow[H_];
    __shared__ __align__(16) ushort featT[64 * 72];
    __shared__ __align__(16) ushort wT[128 * 72];
    __shared__ float h1s[64 * 132];

    const int b = blockIdx.x;
    const int t = threadIdx.x;
    for (int i = t; i < H_; i += 256) { qrow[i] = Q[(size_t)b * H_ + i]; mrow[i] = M[(size_t)b * H_ + i]; }

    const int wrow = t >> 1;
    const int wc0  = (t & 1) * 32;
    if (wrow >= SH_) {
        uint4* dst = (uint4*)&wT[wrow * 72 + wc0];
        const uint4 z = {0u, 0u, 0u, 0u};
        dst[0] = z; dst[1] = z; dst[2] = z; dst[3] = z;
    }
    __syncthreads();

    const int lane = t & 63;
    const int wv   = t >> 6;
    const int quad = lane >> 4;
    const int l15  = lane & 15;
    const int arow = wv * 16 + l15;
    const int s    = t >> 2;
    const int c0   = (t & 3) * 16;

    floatx4 acc[8];
#pragma unroll
    for (int i = 0; i < 8; ++i) acc[i] = (floatx4){0.f, 0.f, 0.f, 0.f};

    for (int hc = 0; hc < H_; hc += 64) {
        float cr[16];
        {
            const float4* csrc = (const float4*)(C + ((size_t)b * S_ + s) * H_ + hc + c0);
            *(float4*)&cr[0]  = csrc[0];
            *(float4*)&cr[4]  = csrc[1];
            *(float4*)&cr[8]  = csrc[2];
            *(float4*)&cr[12] = csrc[3];
        }
#pragma unroll
        for (int seg = 0; seg < 4; ++seg) {
#pragma unroll
            for (int u = 0; u < 16; ++u) {
                const int kk = c0 + u;
                const float c = cr[u];
                const float o = (seg == 0 || seg == 2) ? qrow[hc + kk] : mrow[hc + kk];
                const float v = (seg < 2) ? c * o : fabsf(c - o);
                featT[s * 72 + kk] = f2bf(v);
            }
            if (wrow < SH_) {
                const uint4* src = (const uint4*)(fc1wb + (size_t)wrow * (4 * H_) + seg * H_ + hc + wc0);
                uint4* dst = (uint4*)&wT[wrow * 72 + wc0];
                dst[0] = src[0]; dst[1] = src[1]; dst[2] = src[2]; dst[3] = src[3];
            }
            __syncthreads();
#pragma unroll
            for (int ks = 0; ks < 64; ks += 32) {
                const int ao = ks + quad * 8;
                const bf16x8 af = *(const bf16x8*)&featT[arow * 72 + ao];
#pragma unroll
                for (int nt = 0; nt < 8; ++nt) {
                    const bf16x8 bfr = *(const bf16x8*)&wT[(nt * 16 + l15) * 72 + ao];
                    acc[nt] = __builtin_amdgcn_mfma_f32_16x16x32_bf16(af, bfr, acc[nt], 0, 0, 0);
                }
            }
            __syncthreads();
        }
    }

#pragma unroll
    for (int nt = 0; nt < 8; ++nt) {
        const int col = nt * 16 + l15;
        const float bias = (col < SH_) ? fc1b[col] : 0.f;
#pragma unroll
        for (int r = 0; r < 4; ++r) {
            const int row = wv * 16 + quad * 4 + r;
            h1s[row * 132 + col] = (col < SH_) ? tanhf(acc[nt][r] + bias) : 0.f;
        }
    }
    __syncthreads();
    {
        const int part = t & 3;
        float sum = 0.f;
        for (int k = part; k < SH_; k += 4) sum += h1s[s * 132 + k] * fc2w[k];
        sum += __shfl_xor(sum, 1);
        sum += __shfl_xor(sum, 2);
        if (part == 0) {
            const float logit = sum + fc2b[0];
            G[(size_t)b * S_ + s] = 1.f / (1.f + expf(-logit));
        }
    }
}

// ---------------------------------------------------------------------------
// xg_kernel: one 8-timestep chunk of xg = C@Wih^T. Grid = 64 M-tiles x 6 N-tiles.
// Block tile 128 M x 256 N, K=512 in 8 chunks of 64, double-buffered LDS.
// M-row r of tile mt -> (b, sl): b=(mt*128+r)>>3, sl=(mt*128+r)&7, t = c*8+sl.
// Output layout: xg[(b*8+sl)*1536 + n], bf16.
// ---------------------------------------------------------------------------
__global__ __launch_bounds__(256, 1) void xg_kernel(
    const float* __restrict__ C, const ushort* __restrict__ Wihb,
    ushort* __restrict__ xg, int c)
{
    __shared__ __align__(16) ushort As[2][128 * 72];
    __shared__ __align__(16) ushort Bs[2][256 * 72];

    const int bx = blockIdx.x;
    const int mt = bx & 63;
    const int ntile = bx >> 6;
    const int t = threadIdx.x;
    const int lane = t & 63;
    const int wv   = t >> 6;
    const int quad = lane >> 4;
    const int l15  = lane & 15;

    // A staging: row = t>>1 (0..127), half = t&1 -> 32 cols
    const int ar = t >> 1;
    const int ah = (t & 1) * 32;
    const int grow = mt * 128 + ar;
    const float* aptr = C + ((size_t)(grow >> 3) * S_ + c * 8 + (grow & 7)) * H_ + ah;
    // B staging: row = t (0..255), 8 groups of 8
    const ushort* bptr = Wihb + (size_t)(ntile * 256 + t) * H_;

    floatx4 acc[2][16];
#pragma unroll
    for (int i = 0; i < 2; ++i)
#pragma unroll
        for (int j = 0; j < 16; ++j) acc[i][j] = (floatx4){0.f, 0.f, 0.f, 0.f};

    // prologue: stage chunk 0
    {
        float av[32];
#pragma unroll
        for (int q = 0; q < 8; ++q) *(float4*)&av[q * 4] = *(const float4*)(aptr + q * 4);
        __align__(16) ushort ab[32];
#pragma unroll
        for (int u = 0; u < 32; ++u) ab[u] = f2bf_fast(av[u]);
        uint4* dst = (uint4*)&As[0][ar * 72 + ah];
        dst[0] = ((uint4*)ab)[0]; dst[1] = ((uint4*)ab)[1];
        dst[2] = ((uint4*)ab)[2]; dst[3] = ((uint4*)ab)[3];
#pragma unroll
        for (int g = 0; g < 8; ++g)
            *(uint4*)&Bs[0][t * 72 + g * 8] = *(const uint4*)(bptr + g * 8);
    }
    __syncthreads();

    for (int kci = 0; kci < 8; ++kci) {
        const int cur = kci & 1;
        float av[32]; uint4 bv[8];
        if (kci < 7) {
            const int kn = (kci + 1) * 64;
#pragma unroll
            for (int q = 0; q < 8; ++q) *(float4*)&av[q * 4] = *(const float4*)(aptr + kn + q * 4);
#pragma unroll
            for (int g = 0; g < 8; ++g) bv[g] = *(const uint4*)(bptr + kn + g * 8);
        }
#pragma unroll
        for (int ks = 0; ks < 64; ks += 32) {
            const int ao = ks + quad * 8;
            const bf16x8 a0 = *(const bf16x8*)&As[cur][(wv * 32 + l15) * 72 + ao];
            const bf16x8 a1 = *(const bf16x8*)&As[cur][(wv * 32 + 16 + l15) * 72 + ao];
#pragma unroll
            for (int nf = 0; nf < 16; ++nf) {
                const bf16x8 bfr = *(const bf16x8*)&Bs[cur][(nf * 16 + l15) * 72 + ao];
                acc[0][nf] = __builtin_amdgcn_mfma_f32_16x16x32_bf16(a0, bfr, acc[0][nf], 0, 0, 0);
                acc[1][nf] = __builtin_amdgcn_mfma_f32_16x16x32_bf16(a1, bfr, acc[1][nf], 0, 0, 0);
            }
        }
        if (kci < 7) {
            __align__(16) ushort ab[32];
#pragma unroll
            for (int u = 0; u < 32; ++u) ab[u] = f2bf_fast(av[u]);
            uint4* dst = (uint4*)&As[cur ^ 1][ar * 72 + ah];
            dst[0] = ((uint4*)ab)[0]; dst[1] = ((uint4*)ab)[1];
            dst[2] = ((uint4*)ab)[2]; dst[3] = ((uint4*)ab)[3];
#pragma unroll
            for (int g = 0; g < 8; ++g)
                *(uint4*)&Bs[cur ^ 1][t * 72 + g * 8] = bv[g];
        }
        __syncthreads();
    }

    // epilogue: write bf16 xg
#pragma unroll
    for (int mf = 0; mf < 2; ++mf) {
#pragma unroll
        for (int nf = 0; nf < 16; ++nf) {
            const int n = ntile * 256 + nf * 16 + l15;
#pragma unroll
            for (int r = 0; r < 4; ++r) {
                const int row = mt * 128 + wv * 32 + mf * 16 + quad * 4 + r;
                xg[(size_t)row * 1536 + n] = f2bf(acc[mf][nf][r]);
            }
        }
    }
}

// ---------------------------------------------------------------------------
// scan_step: grid = 256 = 16 j-tiles x 16 b-tiles. gates = xg + h@Whh^T.
// h bf16 hi+lo, double-buffered across steps; LDS chunk pipeline within.
// ---------------------------------------------------------------------------
__global__ __launch_bounds__(256, 1) void scan_step(
    const ushort* __restrict__ xg, const ushort* __restrict__ Whhb,
    const float* __restrict__ bih, const float* __restrict__ bhh,
    const float* __restrict__ G,
    const ushort* __restrict__ hhi_r, const ushort* __restrict__ hlo_r,
    ushort* __restrict__ hhi_w, ushort* __restrict__ hlo_w,
    float* __restrict__ out, int tstep, int sl, int last)
{
    __shared__ __align__(16) ushort Hs[2][2 * 4608];  // buf: hi 64x72 | lo 64x72
    __shared__ __align__(16) ushort Ws[2][6912];      // buf: Whh 96x72
    __shared__ __align__(16) ushort xgs[64 * 96];     // 64 b-rows x (3 gates x 32 j)

    const int bx = blockIdx.x;
    const int jt = bx & 15;
    const int bt = bx >> 4;
    const int jb = jt * 32;
    const int bb = bt * 64;
    const int t  = threadIdx.x;
    const int lane = t & 63;
    const int wv   = t >> 6;
    const int quad = lane >> 4;
    const int l15  = lane & 15;
    const int arow = wv * 16 + l15;

    floatx4 acc_r[2], acc_z[2], acc_xn2[2], acc_hn[2];
#pragma unroll
    for (int i = 0; i < 2; ++i) {
        acc_r[i] = (floatx4){0.f,0.f,0.f,0.f}; acc_z[i]   = (floatx4){0.f,0.f,0.f,0.f};
        acc_xn2[i]=(floatx4){0.f,0.f,0.f,0.f}; acc_hn[i]  = (floatx4){0.f,0.f,0.f,0.f};
    }

    // --- stage xg slice (once per step): 768 uint4, 3 per thread ---
#pragma unroll
    for (int i = 0; i < 3; ++i) {
        const int gid  = i * 256 + t;
        const int seg  = gid >> 2;         // 0..191 = row*3+gate
        const int q    = gid & 3;
        const int row  = seg / 3;
        const int gate = seg - row * 3;
        const ushort* src = xg + ((size_t)(bb + row) * 8 + sl) * 1536 + gate * H_ + jb + q * 8;
        *(uint4*)&xgs[row * 96 + gate * 32 + q * 8] = *(const uint4*)src;
    }
    // --- stage chunk 0 (h + Whh) ---
    {
#pragma unroll
        for (int i = 0; i < 4; ++i) {
            const int gid  = i * 256 + t;
            const int tile = gid >> 9;
            const int rem  = gid & 511;
            const int row  = rem >> 3;
            const int grp  = rem & 7;
            const ushort* src = (tile ? hlo_r : hhi_r) + (size_t)(bb + row) * H_ + grp * 8;
            *(uint4*)&Hs[0][tile * 4608 + row * 72 + grp * 8] = *(const uint4*)src;
        }
#pragma unroll
        for (int i = 0; i < 3; ++i) {
            const int gid = i * 256 + t;
            const int row = gid >> 3;
            const int grp = gid & 7;
            const int gate = row >> 5;
            const int jj   = row & 31;
            const ushort* src = Whhb + (size_t)(gate * H_ + jb + jj) * H_ + grp * 8;
            *(uint4*)&Ws[0][row * 72 + grp * 8] = *(const uint4*)src;
        }
    }
    __syncthreads();

    for (int kci = 0; kci < 8; ++kci) {
        const int cur = kci & 1;
        uint4 hv[4], wvr[3];
        if (kci < 7) {
            const int kn = (kci + 1) * 64;
#pragma unroll
            for (int i = 0; i < 4; ++i) {
                const int gid  = i * 256 + t;
                const int tile = gid >> 9;
                const int rem  = gid & 511;
                const int row  = rem >> 3;
                const int grp  = rem & 7;
                const ushort* src = (tile ? hlo_r : hhi_r) + (size_t)(bb + row) * H_ + kn + grp * 8;
                hv[i] = *(const uint4*)src;
            }
#pragma unroll
            for (int i = 0; i < 3; ++i) {
                const int gid = i * 256 + t;
                const int row = gid >> 3;
                const int grp = gid & 7;
                const int gate = row >> 5;
                const int jj   = row & 31;
                wvr[i] = *(const uint4*)(Whhb + (size_t)(gate * H_ + jb + jj) * H_ + kn + grp * 8);
            }
        }
#pragma unroll
        for (int ks = 0; ks < 64; ks += 32) {
            const int ao = ks + quad * 8;
            const bf16x8 a_hh = *(const bf16x8*)&Hs[cur][arow * 72 + ao];
            const bf16x8 a_hl = *(const bf16x8*)&Hs[cur][4608 + arow * 72 + ao];
#pragma unroll
            for (int nt = 0; nt < 2; ++nt) {
                const int jj = nt * 16 + l15;
                const bf16x8 w_r = *(const bf16x8*)&Ws[cur][(0 * 32 + jj) * 72 + ao];
                const bf16x8 w_z = *(const bf16x8*)&Ws[cur][(1 * 32 + jj) * 72 + ao];
                const bf16x8 w_n = *(const bf16x8*)&Ws[cur][(2 * 32 + jj) * 72 + ao];
                acc_r[nt]  = __builtin_amdgcn_mfma_f32_16x16x32_bf16(a_hh, w_r, acc_r[nt],  0, 0, 0);
                acc_r[nt]  = __builtin_amdgcn_mfma_f32_16x16x32_bf16(a_hl, w_r, acc_r[nt],  0, 0, 0);
                acc_z[nt]  = __builtin_amdgcn_mfma_f32_16x16x32_bf16(a_hh, w_z, acc_z[nt],  0, 0, 0);
                acc_z[nt]  = __builtin_amdgcn_mfma_f32_16x16x32_bf16(a_hl, w_z, acc_z[nt],  0, 0, 0);
                acc_hn[nt] = __builtin_amdgcn_mfma_f32_16x16x32_bf16(a_hh, w_n, acc_hn[nt], 0, 0, 0);
                acc_hn[nt] = __builtin_amdgcn_mfma_f32_16x16x32_bf16(a_hl, w_n, acc_hn[nt], 0, 0, 0);
            }
        }
        if (kci < 7) {
            const int cn = cur ^ 1;
#pragma unroll
            for (int i = 0; i < 4; ++i) {
                const int gid  = i * 256 + t;
                const int tile = gid >> 9;
                const int rem  = gid & 511;
                const int row  = rem >> 3;
                const int grp  = rem & 7;
                *(uint4*)&Hs[cn][tile * 4608 + row * 72 + grp * 8] = hv[i];
            }
#pragma unroll
            for (int i = 0; i < 3; ++i) {
                const int gid = i * 256 + t;
                const int row = gid >> 3;
                const int grp = gid & 7;
                *(uint4*)&Ws[cn][row * 72 + grp * 8] = wvr[i];
            }
        }
        __syncthreads();
    }

    // --- epilogue: gates -> h_new ---
#pragma unroll
    for (int nt = 0; nt < 2; ++nt) {
        const int jc = nt * 16 + l15;          // 0..31 within tile
        const int j  = jb + jc;
        const float br  = bih[j]          + bhh[j];
        const float bz  = bih[H_ + j]     + bhh[H_ + j];
        const float bxn = bih[2 * H_ + j];
        const float bhn = bhh[2 * H_ + j];
#pragma unroll
        for (int r4 = 0; r4 < 4; ++r4) {
            const int bl = wv * 16 + quad * 4 + r4;
            const int b  = bb + bl;
            const size_t idx = (size_t)b * H_ + j;
            const float xr = bf2f(xgs[bl * 96 + 0 * 32 + jc]);
            const float xz = bf2f(xgs[bl * 96 + 1 * 32 + jc]);
            const float xn = bf2f(xgs[bl * 96 + 2 * 32 + jc]);
            const float hold = bf2f(hhi_r[idx]) + bf2f(hlo_r[idx]);
            const float g = G[(size_t)b * S_ + tstep];
            const float rg = 1.f / (1.f + expf(-(acc_r[nt][r4] + xr + br)));
            const float zg = 1.f / (1.f + expf(-(acc_z[nt][r4] + xz + bz)));
            const float ng = tanhf(xn + bxn + rg * (acc_hn[nt][r4] + bhn));
            const float hgru = (1.f - zg) * ng + zg * hold;
            const float hnew = g * hgru + (1.f - g) * hold;
            const ushort hb = f2bf(hnew);
            hhi_w[idx] = hb;
            hlo_w[idx] = f2bf(hnew - bf2f(hb));
            if (last) out[idx] = hnew;
        }
    }
}

extern "C" void kernel_launch(void* const* d_in, const int* in_sizes, int n_in,
                              void* d_out, int out_size, void* d_ws, size_t ws_size,
                              hipStream_t stream) {
    (void)in_sizes; (void)n_in; (void)out_size; (void)ws_size;
    const float* C    = (const float*)d_in[0];
    const float* Q    = (const float*)d_in[1];
    const float* M    = (const float*)d_in[2];
    const float* fc1w = (const float*)d_in[3];
    const float* fc1b = (const float*)d_in[4];
    const float* fc2w = (const float*)d_in[5];
    const float* fc2b = (const float*)d_in[6];
    const float* Wih  = (const float*)d_in[7];
    const float* Whh  = (const float*)d_in[8];
    const float* bih  = (const float*)d_in[9];
    const float* bhh  = (const float*)d_in[10];
    float* out = (float*)d_out;

    char* ws = (char*)d_ws;
    float*  Gbuf  = (float*)ws;                          // 256 KB
    ushort* hhi0  = (ushort*)(ws + 262144);              // 1 MB
    ushort* hlo0  = (ushort*)(ws + 262144 + 1048576);    // 1 MB
    ushort* hhi1  = (ushort*)(ws + 262144 + 2097152);    // 1 MB
    ushort* hlo1  = (ushort*)(ws + 262144 + 3145728);    // 1 MB
    ushort* fc1wb = (ushort*)(ws + 4456448);             // 480 KB
    ushort* Wihb  = (ushort*)(ws + 4947968);             // 1.5 MB
    ushort* Whhb  = (ushort*)(ws + 6520832);             // 1.5 MB
    ushort* xgbuf = (ushort*)(ws + 8093696);             // 25.2 MB (ends ~31.7 MB)

    // h0 = 0: zero buffer 0 (hhi0+hlo0 contiguous; buffer 1 fully written at t=0)
    hipMemsetAsync(hhi0, 0, 2097152, stream);

    prep_w<<<256, 256, 0, stream>>>(fc1w, fc1wb, Wih, Wihb, Whh, Whhb);
    g_kernel<<<B_, 256, 0, stream>>>(C, Q, M, fc1wb, fc1b, fc2w, fc2b, Gbuf);

    for (int c = 0; c < 8; ++c) {
        xg_kernel<<<384, 256, 0, stream>>>(C, Wihb, xgbuf, c);
        for (int sl = 0; sl < 8; ++sl) {
            const int tt = c * 8 + sl;
            const ushort* hr_hi = (tt & 1) ? hhi1 : hhi0;
            const ushort* hr_lo = (tt & 1) ? hlo1 : hlo0;
            ushort* hw_hi = (tt & 1) ? hhi0 : hhi1;
            ushort* hw_lo = (tt & 1) ? hlo0 : hlo1;
            scan_step<<<256, 256, 0, stream>>>(xgbuf, Whhb, bih, bhh, Gbuf,
                                               hr_hi, hr_lo, hw_hi, hw_lo,
                                               out, tt, sl, (tt == S_ - 1) ? 1 : 0);
        }
    }
}